// Round 1
// 3771.581 us; speedup vs baseline: 1.0157x; 1.0157x over previous
//
#include <hip/hip_runtime.h>

// Problem constants
#define B_   16
#define T_   16
#define H_   161
#define W_   181
#define HW_  (H_*W_)     // 29141
#define C_   3
#define F_   21
#define F4_  84
#define CIN_ 24          // C_ + F_ combined conv input channels
#define TSX  32          // tile width  (32 px = 128B rows: coalesced global writes)
#define TSY  8           // tile height (256 threads = 32x8)
#define TPX  34          // tile + halo
#define TPY  10
#define NPOS (TPX*TPY)   // 340
#define TSTR (NPOS+1)    // padded per-channel stride (341)

__device__ __forceinline__ float hsig(float x) {
  return fminf(fmaxf(0.2f * x + 0.5f, 0.0f), 1.0f);
}

__device__ __forceinline__ float fast_tanh(float x) {
  float ax = fabsf(x);
  float t = __expf(-2.0f * ax);
  float r = (1.0f - t) * __builtin_amdgcn_rcpf(1.0f + t);
  return copysignf(r, x);
}

// Weight layout: Wf[kk][ci][f][g]; original output channel oc = g*21 + f.
// One tile read feeds all 84 accumulators (single-pass structure).
__global__ void prep_kernel(const float* __restrict__ k,
                            const float* __restrict__ rk,
                            const float* __restrict__ bias,
                            float* __restrict__ Wf, float* __restrict__ biasf) {
  int i = blockIdx.x * 256 + threadIdx.x;
  if (i < 9 * CIN_ * F_ * 4) {
    int g  = i & 3;
    int r  = i >> 2;
    int f  = r % F_;   r /= F_;
    int ci = r % CIN_; r /= CIN_;
    int kk = r;
    int oc = g * F_ + f;
    float v;
    if (ci < C_) v = k[(kk * C_ + ci) * F4_ + oc];
    else         v = rk[(kk * F_ + (ci - C_)) * F4_ + oc];
    Wf[i] = v;
  }
  if (i < F4_) {
    int g = i & 3;
    int f = i >> 2;
    biasf[i] = bias[g * F_ + f];
  }
}

// One ConvLSTM time step. grid: (ceil(W/32), ceil(H/8), B), block 256 = 32x8.
// h_in/h_out/c_buf CHANNEL-FIRST: idx = (b*F + ch)*HW + y*W + x.
// LDS tile TRANSPOSED: tile[ci][px*TPY + py] -> all wave reads are uniform 2-way
// bank aliasing (free on CDNA4).
// Single pass over the tile: 21 float4 accumulators (84 VGPRs) so each
// ds_read feeds 84 FMAs; __launch_bounds__(256,4) keeps VGPR <= 128.
__global__ void __launch_bounds__(256, 4) step_kernel(
    const float* __restrict__ x,       // (B,T,H,W,C) fp32
    const float* __restrict__ Wf,      // [9][24][21][4] fp32
    const float* __restrict__ biasf,   // [21][4]
    const float* __restrict__ h_in,    // (B,F,H,W) fp32 (ignored if first)
    float* __restrict__ h_out,         // (B,F,H,W) fp32 (not written if last)
    float* __restrict__ c_buf,         // (B,F,H,W) fp32 in-place
    const float* __restrict__ mask,    // (H,W,1) fp32
    float* __restrict__ out,           // (B,H,W,F) fp32 channel-LAST, written if last
    int t, int first, int last) {
  __shared__ float tile[CIN_][TSTR];   // 24*341*4 = 32.7 KB -> 4 blocks/CU

  int b   = blockIdx.z;
  int by0 = blockIdx.y * TSY;
  int bx0 = blockIdx.x * TSX;

  // Stage input tile (halo, zero-padded). Decode pos px-minor (coalesced global
  // reads along x); store transposed at px*TPY+py.
  for (int i = threadIdx.x; i < CIN_ * NPOS; i += 256) {
    int ci  = i / NPOS;
    int pos = i - ci * NPOS;
    int px  = pos % TPX;
    int py  = pos / TPX;
    int gy  = by0 - 1 + py;
    int gx  = bx0 - 1 + px;
    float v = 0.0f;
    if ((unsigned)gy < (unsigned)H_ && (unsigned)gx < (unsigned)W_) {
      if (ci < C_) {
        v = x[(((size_t)(b * T_ + t) * H_ + gy) * W_ + gx) * C_ + ci];
      } else if (!first) {
        v = h_in[(size_t)(b * F_ + (ci - C_)) * HW_ + gy * W_ + gx];
      }
    }
    tile[ci][px * TPY + py] = v;
  }
  __syncthreads();

  int tx = threadIdx.x & 31;   // 0..31
  int ty = threadIdx.x >> 5;   // 0..7
  int gy = by0 + ty;
  int gx = bx0 + tx;
  bool inb = (gy < H_) && (gx < W_);
  size_t q  = (size_t)b * F_ * HW_ + gy * W_ + gx;    // channel-first pixel base
  size_t pf = ((size_t)(b * H_ + gy) * W_ + gx) * F_; // channel-last pixel base
  float m = (last && inb) ? mask[gy * W_ + gx] : 0.0f;

  const float4* b4 = (const float4*)biasf;
  int tbase = tx * TPY + ty;   // transposed (px,py) base for this thread

  float4 acc[F_];
#pragma unroll
  for (int f = 0; f < F_; ++f) acc[f] = b4[f];

#pragma unroll 1
  for (int kk = 0; kk < 9; ++kk) {
    int ky = kk / 3;
    int kx = kk - 3 * ky;
    int pb = tbase + kx * TPY + ky;                   // + ci*TSTR inside
    const float4* wkk = (const float4*)(Wf + (size_t)kk * (CIN_ * F4_));
#pragma unroll 2
    for (int ci = 0; ci < CIN_; ++ci) {
      float v = tile[ci][pb];                         // ds_read_b32, 2-way free
      const float4* w4 = wkk + ci * F_;               // uniform -> s_load
#pragma unroll
      for (int f = 0; f < F_; ++f) {
        float4 w = w4[f];
        acc[f].x = fmaf(v, w.x, acc[f].x);
        acc[f].y = fmaf(v, w.y, acc[f].y);
        acc[f].z = fmaf(v, w.z, acc[f].z);
        acc[f].w = fmaf(v, w.w, acc[f].w);
      }
    }
  }

  if (inb) {
#pragma unroll
    for (int f = 0; f < F_; ++f) {
      size_t idx = q + (size_t)f * HW_;
      float ig = hsig(acc[f].x);
      float fg = hsig(acc[f].y);
      float gg = fast_tanh(acc[f].z);
      float og = hsig(acc[f].w);
      float cp = first ? 0.0f : c_buf[idx];
      float cn = fg * cp + ig * gg;
      float hn = og * fast_tanh(cn);
      c_buf[idx] = cn;
      if (!last) h_out[idx] = hn;
      else       out[pf + f] = hn * m;
    }
  }
}

extern "C" void kernel_launch(void* const* d_in, const int* in_sizes, int n_in,
                              void* d_out, int out_size, void* d_ws, size_t ws_size,
                              hipStream_t stream) {
  const float* x  = (const float*)d_in[0];
  const float* k  = (const float*)d_in[1];
  const float* rk = (const float*)d_in[2];
  const float* bs = (const float*)d_in[3];
  const float* mk = (const float*)d_in[4];
  float* outF = (float*)d_out;   // final output; also odd-step channel-first h buffer

  char* ws = (char*)d_ws;
  float* Wf    = (float*)ws;                       // 18144 fp32
  float* biasf = Wf + 9 * CIN_ * F_ * 4;           // 84 fp32
  size_t off = (((size_t)(9 * CIN_ * F_ * 4 + F4_) * 4) + 255) & ~(size_t)255;
  size_t HWF = (size_t)B_ * H_ * W_ * F_;          // 9,791,376
  float* hA = (float*)(ws + off);                  // even-step h (channel-first)
  float* cB = hA + HWF;                            // cell state (channel-first)
  // total ws use ~78.4 MB

  prep_kernel<<<dim3((9 * CIN_ * F_ * 4 + 255) / 256), 256, 0, stream>>>(
      k, rk, bs, Wf, biasf);

  dim3 grid((W_ + TSX - 1) / TSX, (H_ + TSY - 1) / TSY, B_);  // (6, 21, 16)
  for (int t = 0; t < T_; ++t) {
    // even t: write hA (ws); odd t: write outF. t=15 (odd, last): reads hA,
    // writes ONLY the final channel-last output into outF -> no race on d_out.
    const float* hi = (t & 1) ? hA : outF;
    float* ho       = (t & 1) ? outF : hA;
    step_kernel<<<grid, 256, 0, stream>>>(x, Wf, biasf, hi, ho, cB, mk, outF,
                                          t, (t == 0) ? 1 : 0, (t == T_ - 1) ? 1 : 0);
  }
}

// Round 2
// 2391.780 us; speedup vs baseline: 1.6016x; 1.5769x over previous
//
#include <hip/hip_runtime.h>

// Problem constants
#define B_   16
#define T_   16
#define H_   161
#define W_   181
#define HW_  (H_*W_)     // 29141
#define C_   3
#define F_   21
#define F4_  84
#define CIN_ 24          // C_ + F_ combined conv input channels
#define TSX  32          // tile width
#define TSY  8           // tile height (256 px per block)
#define TPX  34          // tile + halo
#define TPY  10
#define NPOS (TPX*TPY)   // 340
#define NTAP 9
#define MT_  6           // m-tiles of 16 -> 96 gate rows (84 valid, m = f*4+gate)
#define NT_  4           // n-tiles of 16 px per wave (4 waves x 64 px = 256 px)
#define ROWB 128         // LDS bytes per position: 8 slots x 16B (4 ci-groups x {hi,lo})

typedef short bf16x8 __attribute__((ext_vector_type(8)));
typedef float f32x4  __attribute__((ext_vector_type(4)));

__device__ __forceinline__ float hsig(float x) {
  return fminf(fmaxf(0.2f * x + 0.5f, 0.0f), 1.0f);
}

__device__ __forceinline__ float fast_tanh(float x) {
  float ax = fabsf(x);
  float t = __expf(-2.0f * ax);
  float r = (1.0f - t) * __builtin_amdgcn_rcpf(1.0f + t);
  return copysignf(r, x);
}

// round-to-nearest-even fp32 -> bf16 bits
__device__ __forceinline__ unsigned short bf16r(float x) {
  unsigned u = __float_as_uint(x);
  return (unsigned short)((u + 0x7FFFu + ((u >> 16) & 1u)) >> 16);
}

// A-fragment pack: Af[tap][mt][hl][lane][j] (ushort bf16 bits).
// Lane layout for mfma_f32_16x16x32_bf16 A-operand: row m = lane&15,
// k-elem = (lane>>4)*8 + j (k within tap = input channel ci, zero-padded 24..31).
// m = f*4 + gate; original output channel oc = gate*21 + f (Keras i,f,c,o order).
// hl=0: bf16(w) ; hl=1: bf16(w - float(bf16(w))) (split-lo term).
__global__ void prep_kernel(const float* __restrict__ k,
                            const float* __restrict__ rk,
                            const float* __restrict__ bias,
                            unsigned short* __restrict__ Af,
                            float* __restrict__ bias4) {
  int i = blockIdx.x * 256 + threadIdx.x;
  if (i < NTAP * MT_ * 2 * 64 * 8) {
    int j    = i & 7;
    int lane = (i >> 3) & 63;
    int hl   = (i >> 9) & 1;
    int mtp  = i >> 10;          // tap*MT_ + mt
    int mt   = mtp % MT_;
    int tap  = mtp / MT_;
    int m    = mt * 16 + (lane & 15);
    int ci   = (lane >> 4) * 8 + j;
    int f    = m >> 2, gate = m & 3;
    float w = 0.0f;
    if (f < F_ && ci < CIN_) {
      int oc = gate * F_ + f;
      if (ci < C_) w = k[(tap * C_ + ci) * F4_ + oc];
      else         w = rk[(tap * F_ + (ci - C_)) * F4_ + oc];
    }
    unsigned short hb = bf16r(w);
    unsigned short outv;
    if (hl == 0) outv = hb;
    else {
      float hf = __uint_as_float((unsigned)hb << 16);
      outv = bf16r(w - hf);
    }
    Af[i] = outv;
  }
  if (i < 96) {   // bias4[f][gate], f padded to 24
    int f = i >> 2, gate = i & 3;
    bias4[i] = (f < F_) ? bias[gate * F_ + f] : 0.0f;
  }
}

// One ConvLSTM step via split-bf16 MFMA implicit GEMM.
// grid (6,21,16), block 256 (4 waves). Each wave: 4 n-tiles (2 rows x 2 halves
// of its 2-row strip) x 6 m-tiles; acc[mt][nt] f32x4 = 4 gates of filter
// f = mt*4 + (lane>>4) at pixel col = lane&15 within the n-tile.
// LDS tile: [pos][slot^(pos&7)][8 bf16], slot = (ci>>3)*2 + {hi,lo}.
__global__ void __launch_bounds__(256, 3) step_kernel(
    const float* __restrict__ x,        // (B,T,H,W,C) fp32
    const unsigned short* __restrict__ Af,
    const float* __restrict__ bias4,    // [24][4]
    const float* __restrict__ h_in,     // (B,F,H,W) fp32
    float* __restrict__ h_out,          // (B,F,H,W) fp32
    float* __restrict__ c_buf,          // (B,F,H,W) fp32 in-place
    const float* __restrict__ mask,     // (H,W,1)
    float* __restrict__ out,            // (B,H,W,F) fp32, last step only
    int t, int first, int last) {
  __shared__ uint4 tileQ[NPOS * 8];     // 43520 B -> 3 blocks/CU
  unsigned char* tile = (unsigned char*)tileQ;

  int b   = blockIdx.z;
  int by0 = blockIdx.y * TSY;
  int bx0 = blockIdx.x * TSX;
  int tid = threadIdx.x;

  // ---- stage input tile as bf16 hi/lo, zero-padded (halo + ci 24..31) ----
  for (int i = tid; i < 32 * NPOS; i += 256) {
    int ci  = i / NPOS;                 // 0..31 (24..31 = zero pad)
    int pos = i - ci * NPOS;
    int py  = pos / TPX;
    int px  = pos - py * TPX;
    int gy  = by0 - 1 + py;
    int gx  = bx0 - 1 + px;
    float v = 0.0f;
    if (ci < CIN_ && (unsigned)gy < (unsigned)H_ && (unsigned)gx < (unsigned)W_) {
      if (ci < C_) {
        v = x[(((size_t)(b * T_ + t) * H_ + gy) * W_ + gx) * C_ + ci];
      } else if (!first) {
        v = h_in[(size_t)(b * F_ + (ci - C_)) * HW_ + gy * W_ + gx];
      }
    }
    unsigned short hb = bf16r(v);
    float hf = __uint_as_float((unsigned)hb << 16);
    unsigned short lb = bf16r(v - hf);
    int g  = ci >> 3, e = ci & 7;
    int sw = pos & 7;
    *(unsigned short*)&tile[pos * ROWB + (((g * 2 + 0) ^ sw) * 16) + e * 2] = hb;
    *(unsigned short*)&tile[pos * ROWB + (((g * 2 + 1) ^ sw) * 16) + e * 2] = lb;
  }
  __syncthreads();

  int lane = tid & 63;
  int wv   = tid >> 6;    // wave 0..3 -> rows {2wv, 2wv+1} of the 32x8 tile
  int ln15 = lane & 15;
  int lg   = lane >> 4;

  f32x4 acc[MT_][NT_];
#pragma unroll
  for (int mt = 0; mt < MT_; ++mt)
#pragma unroll
    for (int nt = 0; nt < NT_; ++nt)
      acc[mt][nt] = (f32x4){0.f, 0.f, 0.f, 0.f};

#pragma unroll 1
  for (int tap = 0; tap < NTAP; ++tap) {
    int ky = tap / 3;
    int kx = tap - 3 * ky;

    // B fragments: one conflict-free ds_read_b128 per (nt, hi/lo)
    bf16x8 bh[NT_], bl[NT_];
#pragma unroll
    for (int nt = 0; nt < NT_; ++nt) {
      int pos = (wv * 2 + (nt >> 1) + ky) * TPX + (nt & 1) * 16 + ln15 + kx;
      int sw  = pos & 7;
      uint4 hv = *(const uint4*)&tile[pos * ROWB + (((lg * 2 + 0) ^ sw) * 16)];
      uint4 lv = *(const uint4*)&tile[pos * ROWB + (((lg * 2 + 1) ^ sw) * 16)];
      bh[nt] = __builtin_bit_cast(bf16x8, hv);
      bl[nt] = __builtin_bit_cast(bf16x8, lv);
    }

#pragma unroll
    for (int mt = 0; mt < MT_; ++mt) {
      const uint4* ap = (const uint4*)Af + (size_t)((tap * MT_ + mt) * 2) * 64 + lane;
      bf16x8 ah = __builtin_bit_cast(bf16x8, ap[0]);    // hi frag
      bf16x8 al = __builtin_bit_cast(bf16x8, ap[64]);   // lo frag
#pragma unroll
      for (int nt = 0; nt < NT_; ++nt) {
        acc[mt][nt] = __builtin_amdgcn_mfma_f32_16x16x32_bf16(ah, bh[nt], acc[mt][nt], 0, 0, 0);
        acc[mt][nt] = __builtin_amdgcn_mfma_f32_16x16x32_bf16(ah, bl[nt], acc[mt][nt], 0, 0, 0);
        acc[mt][nt] = __builtin_amdgcn_mfma_f32_16x16x32_bf16(al, bh[nt], acc[mt][nt], 0, 0, 0);
      }
    }
  }

  // ---- lane-local LSTM epilogue: acc f32x4 = (i,f,c~,o) of filter f ----
#pragma unroll
  for (int mt = 0; mt < MT_; ++mt) {
    int f = mt * 4 + lg;
    if (f < F_) {
      float4 bb = ((const float4*)bias4)[f];
#pragma unroll
      for (int nt = 0; nt < NT_; ++nt) {
        int gy = by0 + wv * 2 + (nt >> 1);
        int gx = bx0 + (nt & 1) * 16 + ln15;
        if (gy < H_ && gx < W_) {
          size_t idx = ((size_t)b * F_ + f) * HW_ + (size_t)gy * W_ + gx;
          float zi = acc[mt][nt][0] + bb.x;
          float zf = acc[mt][nt][1] + bb.y;
          float zc = acc[mt][nt][2] + bb.z;
          float zo = acc[mt][nt][3] + bb.w;
          float ig = hsig(zi);
          float fg = hsig(zf);
          float gg = fast_tanh(zc);
          float og = hsig(zo);
          float cp = first ? 0.0f : c_buf[idx];
          float cn = fg * cp + ig * gg;
          float hn = og * fast_tanh(cn);
          c_buf[idx] = cn;
          if (!last) h_out[idx] = hn;
          else {
            out[((size_t)(b * H_ + gy) * W_ + gx) * F_ + f] =
                hn * mask[(size_t)gy * W_ + gx];
          }
        }
      }
    }
  }
}

extern "C" void kernel_launch(void* const* d_in, const int* in_sizes, int n_in,
                              void* d_out, int out_size, void* d_ws, size_t ws_size,
                              hipStream_t stream) {
  const float* x  = (const float*)d_in[0];
  const float* k  = (const float*)d_in[1];
  const float* rk = (const float*)d_in[2];
  const float* bs = (const float*)d_in[3];
  const float* mk = (const float*)d_in[4];
  float* outF = (float*)d_out;   // final output; also odd-step channel-first h buffer

  char* ws = (char*)d_ws;
  unsigned short* Af = (unsigned short*)ws;          // 55296 ushort = 110592 B
  float* bias4 = (float*)(ws + 110592);              // 384 B
  size_t off = (size_t)((110592 + 384 + 255) & ~255);
  size_t HWF = (size_t)B_ * H_ * W_ * F_;            // 9,791,376
  float* hA = (float*)(ws + off);                    // even-step h (channel-first)
  float* cB = hA + HWF;                              // cell state (channel-first)

  prep_kernel<<<dim3((NTAP * MT_ * 2 * 64 * 8 + 255) / 256), 256, 0, stream>>>(
      k, rk, bs, Af, bias4);

  dim3 grid((W_ + TSX - 1) / TSX, (H_ + TSY - 1) / TSY, B_);  // (6, 21, 16)
  for (int t = 0; t < T_; ++t) {
    const float* hi = (t & 1) ? hA : outF;
    float* ho       = (t & 1) ? outF : hA;
    step_kernel<<<grid, 256, 0, stream>>>(x, Af, bias4, hi, ho, cB, mk, outF,
                                          t, (t == 0) ? 1 : 0, (t == T_ - 1) ? 1 : 0);
  }
}

// Round 4
// 1608.484 us; speedup vs baseline: 2.3815x; 1.4870x over previous
//
#include <hip/hip_runtime.h>

// Problem constants
#define B_   16
#define T_   16
#define H_   161
#define W_   181
#define HW_  (H_*W_)     // 29141
#define C_   3
#define F_   21
#define F4_  84
#define TSX  32          // tile width
#define TSY  8           // tile height (256 px per block)
#define TPX  34          // tile + halo
#define TPY  10
#define NPOS (TPX*TPY)   // 340
#define NTAP 9
#define MT_  6           // m-tiles of 16 -> 96 gate rows (m = f*4+gate)
#define NT_  4           // n-tiles of 16 px per wave-row-group
#define ROWB 128         // LDS bytes per position: 8 slots x 16B (4 k-groups x {hi,lo})
// ci map: 0..20 = h channels (recurrent), 21..23 = zero pad, 24..26 = x, 27..31 = zero pad
#define GH_LO ((size_t)B_ * 3 * HW_)   // uint4 elements per plane (hi or lo) = 1,398,768

typedef short bf16x8 __attribute__((ext_vector_type(8)));
typedef float f32x4  __attribute__((ext_vector_type(4)));

__device__ __forceinline__ float hsig(float x) {
  return fminf(fmaxf(0.2f * x + 0.5f, 0.0f), 1.0f);
}

__device__ __forceinline__ float fast_tanh(float x) {
  float ax = fabsf(x);
  float t = __expf(-2.0f * ax);
  float r = (1.0f - t) * __builtin_amdgcn_rcpf(1.0f + t);
  return copysignf(r, x);
}

// round-to-nearest-even fp32 -> bf16 bits
__device__ __forceinline__ unsigned short bf16r(float x) {
  unsigned u = __float_as_uint(x);
  return (unsigned short)((u + 0x7FFFu + ((u >> 16) & 1u)) >> 16);
}
__device__ __forceinline__ void bsplit(float v, unsigned short& hi, unsigned short& lo) {
  hi = bf16r(v);
  float hf = __uint_as_float((unsigned)hi << 16);
  lo = bf16r(v - hf);
}

// A-fragment pack: Af[tap][mt][hl][lane] (uint4 = 8 bf16).
// mfma_f32_16x16x32_bf16 A layout (HW-verified round 2): row m = lane&15,
// k = (lane>>4)*8 + j. m = f*4 + gate; oc = gate*21 + f (Keras i,f,c,o).
__global__ void prep_kernel(const float* __restrict__ k,
                            const float* __restrict__ rk,
                            const float* __restrict__ bias,
                            unsigned short* __restrict__ Af,
                            float* __restrict__ bias4) {
  int i = blockIdx.x * 256 + threadIdx.x;
  if (i < NTAP * MT_ * 2 * 64 * 8) {
    int j    = i & 7;
    int lane = (i >> 3) & 63;
    int hl   = (i >> 9) & 1;
    int mtp  = i >> 10;          // tap*MT_ + mt
    int mt   = mtp % MT_;
    int tap  = mtp / MT_;
    int m    = mt * 16 + (lane & 15);
    int ci   = (lane >> 4) * 8 + j;
    int f    = m >> 2, gate = m & 3;
    float w = 0.0f;
    if (f < F_) {
      int oc = gate * F_ + f;
      if (ci < F_)                  w = rk[(tap * F_ + ci) * F4_ + oc];        // h channels
      else if (ci >= 24 && ci < 27) w = k[(tap * C_ + (ci - 24)) * F4_ + oc];  // x channels
    }
    unsigned short hb = bf16r(w);
    unsigned short outv;
    if (hl == 0) outv = hb;
    else {
      float hf = __uint_as_float((unsigned)hb << 16);
      outv = bf16r(w - hf);
    }
    Af[i] = outv;
  }
  if (i < 96) {   // bias4[f][gate], f padded to 24
    int f = i >> 2, gate = i & 3;
    bias4[i] = (f < F_) ? bias[gate * F_ + f] : 0.0f;
  }
}

// ---------------- packed-h path (needs ~123 MiB ws) ----------------
// grid (6,21,16), block 512 (8 waves). wv>>1 = pixel-row pair (0..3),
// wv&1 = m-half (3 m-tiles each) -> acc 3x4 f32x4 = 48 regs/wave.
// h exchanged between steps as pre-split bf16 hi/lo in MFMA slot layout
// (ghA/ghB double buffer): staging is pure 16B copies, conflict-free.
__global__ void __launch_bounds__(512, 4) step_kernel_p(
    const float* __restrict__ x,        // (B,T,H,W,C) fp32
    const uint4* __restrict__ Af,       // [9][6][2][64] uint4
    const float* __restrict__ bias4,    // [24][4]
    const uint4* __restrict__ g_in,     // h bf16 hi/lo planes (prev step)
    uint4* __restrict__ g_out,          // h bf16 hi/lo planes (this step)
    float* __restrict__ c_buf,          // (B,21,HW) fp32 in-place
    const float* __restrict__ mask,     // (H,W,1)
    float* __restrict__ out,            // (B,H,W,21) fp32, last step only
    int t, int first, int last) {
  __shared__ uint4 tileQ[NPOS * 8];     // 43520 B
  unsigned char* tile = (unsigned char*)tileQ;
  unsigned short* bh16 = (unsigned short*)tileQ;   // epilogue bounce hi: [256][24]
  unsigned short* bl16 = bh16 + 256 * 24;          // bounce lo (offset 12288 B)

  int b   = blockIdx.z;
  int by0 = blockIdx.y * TSY;
  int bx0 = blockIdx.x * TSX;
  int tid = threadIdx.x;

  // ---- stage tile: h groups are raw 16B copies; x converted on the fly ----
  for (int i = tid; i < 6 * NPOS + NPOS; i += 512) {
    if (i < 6 * NPOS) {
      int slot = i / NPOS;              // g*2+hl, g=0..2 (h), hl in {0,1}
      int pos  = i - slot * NPOS;
      int g  = slot >> 1, hl = slot & 1;
      int py = pos / TPX, px = pos - py * TPX;
      int gy = by0 - 1 + py, gx = bx0 - 1 + px;
      uint4 v = {0u, 0u, 0u, 0u};
      if (!first && (unsigned)gy < (unsigned)H_ && (unsigned)gx < (unsigned)W_) {
        v = g_in[(size_t)hl * GH_LO + (size_t)(b * 3 + g) * HW_ + gy * W_ + gx];
      }
      *(uint4*)&tile[pos * ROWB + ((slot ^ (pos & 7)) * 16)] = v;
    } else {
      int pos = i - 6 * NPOS;
      int py = pos / TPX, px = pos - py * TPX;
      int gy = by0 - 1 + py, gx = bx0 - 1 + px;
      float x0 = 0.f, x1 = 0.f, x2 = 0.f;
      if ((unsigned)gy < (unsigned)H_ && (unsigned)gx < (unsigned)W_) {
        const float* xp = x + (((size_t)(b * T_ + t) * H_ + gy) * W_ + gx) * C_;
        x0 = xp[0]; x1 = xp[1]; x2 = xp[2];
      }
      unsigned short h0, h1, h2, l0, l1, l2;
      bsplit(x0, h0, l0); bsplit(x1, h1, l1); bsplit(x2, h2, l2);
      uint4 vh = {(unsigned)h0 | ((unsigned)h1 << 16), (unsigned)h2, 0u, 0u};
      uint4 vl = {(unsigned)l0 | ((unsigned)l1 << 16), (unsigned)l2, 0u, 0u};
      int sw = pos & 7;
      *(uint4*)&tile[pos * ROWB + ((6 ^ sw) * 16)] = vh;
      *(uint4*)&tile[pos * ROWB + ((7 ^ sw) * 16)] = vl;
    }
  }
  __syncthreads();

  int lane = tid & 63;
  int wv   = tid >> 6;     // 0..7
  int wvn  = wv >> 1;      // pixel-row pair 0..3
  int wvm  = wv & 1;       // m-half 0..1
  int ln15 = lane & 15;
  int lg   = lane >> 4;

  f32x4 acc[3][NT_];
#pragma unroll
  for (int mt = 0; mt < 3; ++mt)
#pragma unroll
    for (int nt = 0; nt < NT_; ++nt)
      acc[mt][nt] = (f32x4){0.f, 0.f, 0.f, 0.f};

#pragma unroll 1
  for (int tap = 0; tap < NTAP; ++tap) {
    int ky = tap / 3;
    int kx = tap - 3 * ky;

    bf16x8 bh[NT_], bl[NT_];
#pragma unroll
    for (int nt = 0; nt < NT_; ++nt) {
      int pos = (wvn * 2 + (nt >> 1) + ky) * TPX + (nt & 1) * 16 + ln15 + kx;
      int sw  = pos & 7;
      uint4 hv = *(const uint4*)&tile[pos * ROWB + (((lg * 2 + 0) ^ sw) * 16)];
      uint4 lv = *(const uint4*)&tile[pos * ROWB + (((lg * 2 + 1) ^ sw) * 16)];
      bh[nt] = __builtin_bit_cast(bf16x8, hv);
      bl[nt] = __builtin_bit_cast(bf16x8, lv);
    }

#pragma unroll
    for (int mt = 0; mt < 3; ++mt) {
      const uint4* ap = Af + (size_t)((tap * MT_ + (wvm * 3 + mt)) * 2) * 64 + lane;
      bf16x8 ah = __builtin_bit_cast(bf16x8, ap[0]);
      bf16x8 al = __builtin_bit_cast(bf16x8, ap[64]);
#pragma unroll
      for (int nt = 0; nt < NT_; ++nt) {
        acc[mt][nt] = __builtin_amdgcn_mfma_f32_16x16x32_bf16(ah, bh[nt], acc[mt][nt], 0, 0, 0);
        acc[mt][nt] = __builtin_amdgcn_mfma_f32_16x16x32_bf16(ah, bl[nt], acc[mt][nt], 0, 0, 0);
        acc[mt][nt] = __builtin_amdgcn_mfma_f32_16x16x32_bf16(al, bh[nt], acc[mt][nt], 0, 0, 0);
      }
    }
  }

  __syncthreads();   // tile consumed; reuse LDS as epilogue bounce

  // ---- lane-local LSTM epilogue; h -> bounce LDS as split bf16 ----
#pragma unroll
  for (int mt = 0; mt < 3; ++mt) {
    int f = (wvm * 3 + mt) * 4 + lg;    // 0..23 (21..23 -> exact zero h)
    float4 bb = ((const float4*)bias4)[f];
#pragma unroll
    for (int nt = 0; nt < NT_; ++nt) {
      int py = wvn * 2 + (nt >> 1);
      int px = (nt & 1) * 16 + ln15;
      int gy = by0 + py, gx = bx0 + px;
      if (gy < H_ && gx < W_) {
        int    pixL = py * TSX + px;
        size_t gpix = (size_t)gy * W_ + gx;
        float zi = acc[mt][nt][0] + bb.x;
        float zf = acc[mt][nt][1] + bb.y;
        float zc = acc[mt][nt][2] + bb.z;
        float zo = acc[mt][nt][3] + bb.w;
        float ig = hsig(zi);
        float fg = hsig(zf);
        float gg = fast_tanh(zc);
        float og = hsig(zo);
        float cp = (first || f >= F_) ? 0.0f
                                      : c_buf[((size_t)b * F_ + f) * HW_ + gpix];
        float cn = fg * cp + ig * gg;
        float hn = og * fast_tanh(cn);
        if (f < F_ && !last) c_buf[((size_t)b * F_ + f) * HW_ + gpix] = cn;
        if (last) {
          if (f < F_)
            out[((size_t)(b * H_ + gy) * W_ + gx) * F_ + f] = hn * mask[gpix];
        } else {
          unsigned short hh, hlw;
          bsplit(hn, hh, hlw);
          bh16[pixL * 24 + f] = hh;
          bl16[pixL * 24 + f] = hlw;
        }
      }
    }
  }

  if (last) return;
  __syncthreads();

  // ---- pack bounce -> g_out (coalesced 16B stores) ----
  for (int i = tid; i < 256 * 3 * 2; i += 512) {
    int hl   = (i >= 768) ? 1 : 0;
    int j    = i - hl * 768;
    int g    = j >> 8;
    int pixL = j & 255;
    int py = pixL >> 5, px = pixL & 31;
    int gy = by0 + py, gx = bx0 + px;
    if (gy < H_ && gx < W_) {
      const unsigned short* src = (hl ? bl16 : bh16) + pixL * 24 + g * 8;
      uint4 v = *(const uint4*)src;
      g_out[(size_t)hl * GH_LO + (size_t)(b * 3 + g) * HW_ + (size_t)gy * W_ + gx] = v;
    }
  }
}

// ---------------- fallback path (round-2 proven kernel, new ci map, ~78 MB ws) ----
__global__ void __launch_bounds__(256, 3) step_kernel_f(
    const float* __restrict__ x,
    const uint4* __restrict__ Af,
    const float* __restrict__ bias4,
    const float* __restrict__ h_in,     // (B,F,HW) fp32
    float* __restrict__ h_out,          // (B,F,HW) fp32
    float* __restrict__ c_buf,
    const float* __restrict__ mask,
    float* __restrict__ out,
    int t, int first, int last) {
  __shared__ uint4 tileQ[NPOS * 8];
  unsigned char* tile = (unsigned char*)tileQ;

  int b   = blockIdx.z;
  int by0 = blockIdx.y * TSY;
  int bx0 = blockIdx.x * TSX;
  int tid = threadIdx.x;

  for (int i = tid; i < 32 * NPOS; i += 256) {
    int ci  = i / NPOS;
    int pos = i - ci * NPOS;
    int py = pos / TPX, px = pos - py * TPX;
    int gy = by0 - 1 + py, gx = bx0 - 1 + px;
    float v = 0.0f;
    if ((unsigned)gy < (unsigned)H_ && (unsigned)gx < (unsigned)W_) {
      if (ci < F_) {
        if (!first) v = h_in[(size_t)(b * F_ + ci) * HW_ + gy * W_ + gx];
      } else if (ci >= 24 && ci < 27) {
        v = x[(((size_t)(b * T_ + t) * H_ + gy) * W_ + gx) * C_ + (ci - 24)];
      }
    }
    unsigned short hb, lb;
    bsplit(v, hb, lb);
    int g  = ci >> 3, e = ci & 7, sw = pos & 7;
    *(unsigned short*)&tile[pos * ROWB + (((g * 2 + 0) ^ sw) * 16) + e * 2] = hb;
    *(unsigned short*)&tile[pos * ROWB + (((g * 2 + 1) ^ sw) * 16) + e * 2] = lb;
  }
  __syncthreads();

  int lane = tid & 63;
  int wv   = tid >> 6;    // 0..3 -> pixel-row pair
  int ln15 = lane & 15;
  int lg   = lane >> 4;

  f32x4 acc[MT_][NT_];
#pragma unroll
  for (int mt = 0; mt < MT_; ++mt)
#pragma unroll
    for (int nt = 0; nt < NT_; ++nt)
      acc[mt][nt] = (f32x4){0.f, 0.f, 0.f, 0.f};

#pragma unroll 1
  for (int tap = 0; tap < NTAP; ++tap) {
    int ky = tap / 3;
    int kx = tap - 3 * ky;

    bf16x8 bh[NT_], bl[NT_];
#pragma unroll
    for (int nt = 0; nt < NT_; ++nt) {
      int pos = (wv * 2 + (nt >> 1) + ky) * TPX + (nt & 1) * 16 + ln15 + kx;
      int sw  = pos & 7;
      uint4 hv = *(const uint4*)&tile[pos * ROWB + (((lg * 2 + 0) ^ sw) * 16)];
      uint4 lv = *(const uint4*)&tile[pos * ROWB + (((lg * 2 + 1) ^ sw) * 16)];
      bh[nt] = __builtin_bit_cast(bf16x8, hv);
      bl[nt] = __builtin_bit_cast(bf16x8, lv);
    }

#pragma unroll
    for (int mt = 0; mt < MT_; ++mt) {
      const uint4* ap = Af + (size_t)((tap * MT_ + mt) * 2) * 64 + lane;
      bf16x8 ah = __builtin_bit_cast(bf16x8, ap[0]);
      bf16x8 al = __builtin_bit_cast(bf16x8, ap[64]);
#pragma unroll
      for (int nt = 0; nt < NT_; ++nt) {
        acc[mt][nt] = __builtin_amdgcn_mfma_f32_16x16x32_bf16(ah, bh[nt], acc[mt][nt], 0, 0, 0);
        acc[mt][nt] = __builtin_amdgcn_mfma_f32_16x16x32_bf16(ah, bl[nt], acc[mt][nt], 0, 0, 0);
        acc[mt][nt] = __builtin_amdgcn_mfma_f32_16x16x32_bf16(al, bh[nt], acc[mt][nt], 0, 0, 0);
      }
    }
  }

#pragma unroll
  for (int mt = 0; mt < MT_; ++mt) {
    int f = mt * 4 + lg;
    if (f < F_) {
      float4 bb = ((const float4*)bias4)[f];
#pragma unroll
      for (int nt = 0; nt < NT_; ++nt) {
        int gy = by0 + wv * 2 + (nt >> 1);
        int gx = bx0 + (nt & 1) * 16 + ln15;
        if (gy < H_ && gx < W_) {
          size_t idx = ((size_t)b * F_ + f) * HW_ + (size_t)gy * W_ + gx;
          float zi = acc[mt][nt][0] + bb.x;
          float zf = acc[mt][nt][1] + bb.y;
          float zc = acc[mt][nt][2] + bb.z;
          float zo = acc[mt][nt][3] + bb.w;
          float ig = hsig(zi);
          float fg = hsig(zf);
          float gg = fast_tanh(zc);
          float og = hsig(zo);
          float cp = first ? 0.0f : c_buf[idx];
          float cn = fg * cp + ig * gg;
          float hn = og * fast_tanh(cn);
          c_buf[idx] = cn;
          if (!last) h_out[idx] = hn;
          else {
            out[((size_t)(b * H_ + gy) * W_ + gx) * F_ + f] =
                hn * mask[(size_t)gy * W_ + gx];
          }
        }
      }
    }
  }
}

extern "C" void kernel_launch(void* const* d_in, const int* in_sizes, int n_in,
                              void* d_out, int out_size, void* d_ws, size_t ws_size,
                              hipStream_t stream) {
  const float* x  = (const float*)d_in[0];
  const float* k  = (const float*)d_in[1];
  const float* rk = (const float*)d_in[2];
  const float* bs = (const float*)d_in[3];
  const float* mk = (const float*)d_in[4];
  float* outF = (float*)d_out;

  char* ws = (char*)d_ws;
  unsigned short* Af = (unsigned short*)ws;          // 55296 ushort = 110592 B
  float* bias4 = (float*)(ws + 110592);              // 384 B
  size_t off = (size_t)((110592 + 384 + 255) & ~255);  // 111104
  size_t HWF = (size_t)B_ * H_ * W_ * F_;            // 9,791,376

  prep_kernel<<<dim3((NTAP * MT_ * 2 * 64 * 8 + 255) / 256), 256, 0, stream>>>(
      k, rk, bs, Af, bias4);

  dim3 grid((W_ + TSX - 1) / TSX, (H_ + TSY - 1) / TSY, B_);  // (6, 21, 16)

  size_t need_packed = off + (size_t)4 * GH_LO * 16 + HWF * 4;  // ~128.8 MB

  if (ws_size >= need_packed) {
    // packed-h path: ghA/ghB = split-bf16 h planes, c fp32
    uint4* ghA = (uint4*)(ws + off);
    uint4* ghB = ghA + 2 * GH_LO;
    float* cB  = (float*)(ghB + 2 * GH_LO);
    for (int t = 0; t < T_; ++t) {
      const uint4* gin = (t & 1) ? ghB : ghA;
      uint4* gout      = (t & 1) ? ghA : ghB;
      step_kernel_p<<<grid, 512, 0, stream>>>(x, (const uint4*)Af, bias4, gin, gout,
                                              cB, mk, outF, t,
                                              (t == 0) ? 1 : 0, (t == T_ - 1) ? 1 : 0);
    }
  } else {
    // fallback (round-2 proven): fp32 h ping-pong via ws + outF, ~78.4 MB
    float* hA = (float*)(ws + off);
    float* cB = hA + HWF;
    for (int t = 0; t < T_; ++t) {
      const float* hi = (t & 1) ? hA : outF;
      float* ho       = (t & 1) ? outF : hA;
      step_kernel_f<<<grid, 256, 0, stream>>>(x, (const uint4*)Af, bias4, hi, ho,
                                              cB, mk, outF, t,
                                              (t == 0) ? 1 : 0, (t == T_ - 1) ? 1 : 0);
    }
  }
}